// Round 7
// baseline (195.336 us; speedup 1.0000x reference)
//
#include <hip/hip_runtime.h>

#define FH 50
#define FW 75
#define FC 512
#define NPOOL 7
#define NXCD 8

typedef float f32x4 __attribute__((ext_vector_type(4)));

typedef const __attribute__((address_space(1))) void g_void;
typedef __attribute__((address_space(3))) void l_void;

__device__ __forceinline__ float uniform_f(float x) {
    return __int_as_float(__builtin_amdgcn_readfirstlane(__float_as_int(x)));
}

__global__ __launch_bounds__(128) void roi_pool_kernel(
    const float* __restrict__ fmap,     // (1, FH, FW, FC)
    const float* __restrict__ rois,     // (N, 4) = x1,y1,x2,y2 image coords
    const int*   __restrict__ img_size, // [800, 1200]
    float* __restrict__ out,            // (N, 7, 7, FC)
    int N)
{
    // 16 corners x 512 channels x 4B = 32 KiB staging
    __shared__ float lds[16 * FC];

    // ---- bijective XCD-chunked swizzle: one ROI's blocks -> one XCD ----
    const int nwg = gridDim.x;
    const int q = nwg / NXCD, r = nwg % NXCD;
    const int xcd = blockIdx.x % NXCD, local = blockIdx.x / NXCD;
    const int w = (xcd < r ? xcd * (q + 1) : r * (q + 1) + (xcd - r) * q) + local;

    const int n  = w / (NPOOL * NPOOL);
    const int p  = w % (NPOOL * NPOOL);
    const int py = p / NPOOL;
    const int px = p % NPOOL;
    if (n >= N) return;   // no barrier anywhere -> early return is safe

    const float img_h = (float)(img_size[0] - 1);
    const float img_w = (float)(img_size[1] - 1);

    const float rx1 = rois[n * 4 + 0];
    const float ry1 = rois[n * 4 + 1];
    const float rx2 = rois[n * 4 + 2];
    const float ry2 = rois[n * 4 + 3];

    const float fh = (float)(FH - 1);   // 49
    const float fw = (float)(FW - 1);   // 74
    const float stepy = (ry2 - ry1) / img_h * fh * (1.0f / 13.0f);
    const float stepx = (rx2 - rx1) / img_w * fw * (1.0f / 13.0f);
    const float basey = ry1 / img_h * fh;
    const float basex = rx1 / img_w * fw;

    // ---- per-sample coordinate math (block-uniform, hoisted to SGPR) ----
    int   off[16];          // [sample*4 + corner] element offsets
    float wy_[4], wx_[4], mv_[4];
    #pragma unroll
    for (int kk = 0; kk < 4; ++kk) {
        const int iy = py * 2 + (kk >> 1);
        const int ix = px * 2 + (kk & 1);
        const float ys = basey + (float)iy * stepy;
        const float xs = basex + (float)ix * stepx;
        const bool valid = (ys >= 0.0f) & (ys <= fh) & (xs >= 0.0f) & (xs <= fw);
        mv_[kk] = uniform_f(valid ? 1.0f : 0.0f);

        const float y0f = floorf(ys);
        const float x0f = floorf(xs);
        wy_[kk] = uniform_f(ys - y0f);
        wx_[kk] = uniform_f(xs - x0f);
        int y0i = (int)y0f; y0i = min(max(y0i, 0), FH - 1);
        int x0i = (int)x0f; x0i = min(max(x0i, 0), FW - 1);
        const int y1i = min(y0i + 1, FH - 1);
        const int x1i = min(x0i + 1, FW - 1);
        off[kk * 4 + 0] = __builtin_amdgcn_readfirstlane((y0i * FW + x0i) * FC);
        off[kk * 4 + 1] = __builtin_amdgcn_readfirstlane((y0i * FW + x1i) * FC);
        off[kk * 4 + 2] = __builtin_amdgcn_readfirstlane((y1i * FW + x0i) * FC);
        off[kk * 4 + 3] = __builtin_amdgcn_readfirstlane((y1i * FW + x1i) * FC);
    }

    const int t  = threadIdx.x;
    const int ch = t * 4;                    // this thread's 4 channels
    const int wavebase = (t >> 6) << 8;      // wave 0 -> 0, wave 1 -> 256 floats

    // ---- Stage ALL 16 corners into LDS via async global->LDS DMA.     ----
    // ---- Results don't occupy VGPRs, so all 16 stay outstanding under ----
    // ---- a single vmcnt(0).  Wave w stages channels [256w, 256w+256)  ----
    // ---- at lds[c*512 + 256w] (HW writes wave-uniform base + lane*16, ----
    // ---- which equals linear channel order).  Each wave later reads   ----
    // ---- only its own region -> NO __syncthreads needed.              ----
    const float* src = fmap + ch;
    #pragma unroll
    for (int c = 0; c < 16; ++c) {
        __builtin_amdgcn_global_load_lds(
            (g_void*)(src + off[c]),
            (l_void*)&lds[c * FC + wavebase],
            16, 0, 0);
    }
    asm volatile("s_waitcnt vmcnt(0)" ::: "memory");

    // ---- Interpolate + max from LDS ----
    f32x4 m = (f32x4){-INFINITY, -INFINITY, -INFINITY, -INFINITY};
    #pragma unroll
    for (int kk = 0; kk < 4; ++kk) {
        const f32x4 tl = *(const f32x4*)&lds[(kk * 4 + 0) * FC + ch];
        const f32x4 tr = *(const f32x4*)&lds[(kk * 4 + 1) * FC + ch];
        const f32x4 bl = *(const f32x4*)&lds[(kk * 4 + 2) * FC + ch];
        const f32x4 br = *(const f32x4*)&lds[(kk * 4 + 3) * FC + ch];
        const float wyv = wy_[kk], wxv = wx_[kk], mv = mv_[kk];
        f32x4 top = tl + wxv * (tr - tl);
        f32x4 bot = bl + wxv * (br - bl);
        f32x4 v = top + wyv * (bot - top);
        v *= mv;
        m.x = fmaxf(m.x, v.x);
        m.y = fmaxf(m.y, v.y);
        m.z = fmaxf(m.z, v.z);
        m.w = fmaxf(m.w, v.w);
    }

    f32x4* dst = (f32x4*)(out + (((long)n * NPOOL + py) * NPOOL + px) * FC + ch);
    __builtin_nontemporal_store(m, dst);
}

extern "C" void kernel_launch(void* const* d_in, const int* in_sizes, int n_in,
                              void* d_out, int out_size, void* d_ws, size_t ws_size,
                              hipStream_t stream) {
    const float* fmap     = (const float*)d_in[0];
    const float* rois     = (const float*)d_in[1];
    const int*   img_size = (const int*)d_in[2];
    float* out = (float*)d_out;

    const int N = in_sizes[1] / 4;   // rois is (N,4)
    const int blocks = N * NPOOL * NPOOL;
    roi_pool_kernel<<<blocks, 128, 0, stream>>>(fmap, rois, img_size, out, N);
}

// Round 8
// 159.420 us; speedup vs baseline: 1.2253x; 1.2253x over previous
//
#include <hip/hip_runtime.h>

#define FH 50
#define FW 75
#define FC 512
#define NPOOL 7
#define NXCD 8

typedef float f32x4 __attribute__((ext_vector_type(4)));

__device__ __forceinline__ float uniform_f(float x) {
    return __int_as_float(__builtin_amdgcn_readfirstlane(__float_as_int(x)));
}

__global__ __launch_bounds__(128) void roi_pool_kernel(
    const float* __restrict__ fmap,     // (1, FH, FW, FC)
    const float* __restrict__ rois,     // (N, 4) = x1,y1,x2,y2 image coords
    const int*   __restrict__ img_size, // [800, 1200]
    float* __restrict__ out,            // (N, 7, 7, FC)
    int N)
{
    // ---- bijective XCD-chunked swizzle: one ROI's 49 blocks -> one XCD ----
    const int nwg = gridDim.x;
    const int q = nwg / NXCD, r = nwg % NXCD;
    const int xcd = blockIdx.x % NXCD, local = blockIdx.x / NXCD;
    const int w = (xcd < r ? xcd * (q + 1) : r * (q + 1) + (xcd - r) * q) + local;

    const int n  = w / (NPOOL * NPOOL);
    const int p  = w % (NPOOL * NPOOL);
    const int py = p / NPOOL;
    const int px = p % NPOOL;
    if (n >= N) return;

    const float img_h = (float)(img_size[0] - 1);
    const float img_w = (float)(img_size[1] - 1);

    const float rx1 = rois[n * 4 + 0];
    const float ry1 = rois[n * 4 + 1];
    const float rx2 = rois[n * 4 + 2];
    const float ry2 = rois[n * 4 + 3];

    const float fh = (float)(FH - 1);   // 49
    const float fw = (float)(FW - 1);   // 74
    const float stepy = (ry2 - ry1) / img_h * fh * (1.0f / 13.0f);
    const float stepx = (rx2 - rx1) / img_w * fw * (1.0f / 13.0f);
    const float basey = ry1 / img_h * fh;
    const float basex = rx1 / img_w * fw;

    // ---- Phase 1: per-sample offsets + FACTORED bilinear weights ----
    // v = w00*tl + w01*tr + w10*bl + w11*br, mask folded into weights.
    int   off00[4], off01[4], off10[4], off11[4];
    float w00_[4], w01_[4], w10_[4], w11_[4];
    #pragma unroll
    for (int kk = 0; kk < 4; ++kk) {
        const int iy = py * 2 + (kk >> 1);
        const int ix = px * 2 + (kk & 1);
        const float ys = basey + (float)iy * stepy;
        const float xs = basex + (float)ix * stepx;
        const float mv = ((ys >= 0.0f) & (ys <= fh) & (xs >= 0.0f) & (xs <= fw))
                         ? 1.0f : 0.0f;

        const float y0f = floorf(ys);
        const float x0f = floorf(xs);
        const float wy = ys - y0f;
        const float wx = xs - x0f;
        int y0i = (int)y0f; y0i = min(max(y0i, 0), FH - 1);
        int x0i = (int)x0f; x0i = min(max(x0i, 0), FW - 1);
        const int y1i = min(y0i + 1, FH - 1);
        const int x1i = min(x0i + 1, FW - 1);

        w00_[kk] = uniform_f((1.0f - wy) * (1.0f - wx) * mv);
        w01_[kk] = uniform_f((1.0f - wy) * wx * mv);
        w10_[kk] = uniform_f(wy * (1.0f - wx) * mv);
        w11_[kk] = uniform_f(wy * wx * mv);

        off00[kk] = __builtin_amdgcn_readfirstlane((y0i * FW + x0i) * FC);
        off01[kk] = __builtin_amdgcn_readfirstlane((y0i * FW + x1i) * FC);
        off10[kk] = __builtin_amdgcn_readfirstlane((y1i * FW + x0i) * FC);
        off11[kk] = __builtin_amdgcn_readfirstlane((y1i * FW + x1i) * FC);
    }

    const int c4 = threadIdx.x * 4;   // 128 threads * 4 channels = 512
    const float* fm = fmap + c4;

    // ---- Phase 2: issue ALL 16 loads, pin results live ----
    f32x4 tl0, tr0, bl0, br0, tl1, tr1, bl1, br1;
    f32x4 tl2, tr2, bl2, br2, tl3, tr3, bl3, br3;
    tl0 = *(const f32x4*)(fm + off00[0]);
    tr0 = *(const f32x4*)(fm + off01[0]);
    bl0 = *(const f32x4*)(fm + off10[0]);
    br0 = *(const f32x4*)(fm + off11[0]);
    tl1 = *(const f32x4*)(fm + off00[1]);
    tr1 = *(const f32x4*)(fm + off01[1]);
    bl1 = *(const f32x4*)(fm + off10[1]);
    br1 = *(const f32x4*)(fm + off11[1]);
    tl2 = *(const f32x4*)(fm + off00[2]);
    tr2 = *(const f32x4*)(fm + off01[2]);
    bl2 = *(const f32x4*)(fm + off10[2]);
    br2 = *(const f32x4*)(fm + off11[2]);
    tl3 = *(const f32x4*)(fm + off00[3]);
    tr3 = *(const f32x4*)(fm + off01[3]);
    bl3 = *(const f32x4*)(fm + off10[3]);
    br3 = *(const f32x4*)(fm + off11[3]);

    asm volatile("" : "+v"(tl0), "+v"(tr0), "+v"(bl0), "+v"(br0),
                      "+v"(tl1), "+v"(tr1), "+v"(bl1), "+v"(br1),
                      "+v"(tl2), "+v"(tr2), "+v"(bl2), "+v"(br2),
                      "+v"(tl3), "+v"(tr3), "+v"(bl3), "+v"(br3));

    // ---- Phase 3: weighted sums (mul + 3 fma per channel) ----
    const f32x4 v0 = w00_[0] * tl0 + w01_[0] * tr0 + w10_[0] * bl0 + w11_[0] * br0;
    const f32x4 v1 = w00_[1] * tl1 + w01_[1] * tr1 + w10_[1] * bl1 + w11_[1] * br1;
    const f32x4 v2 = w00_[2] * tl2 + w01_[2] * tr2 + w10_[2] * bl2 + w11_[2] * br2;
    const f32x4 v3 = w00_[3] * tl3 + w01_[3] * tr3 + w10_[3] * bl3 + w11_[3] * br3;

    // ---- max over the 2x2 pool window (fuses to v_max3 + v_max) ----
    f32x4 m;
    m.x = fmaxf(fmaxf(fmaxf(v0.x, v1.x), v2.x), v3.x);
    m.y = fmaxf(fmaxf(fmaxf(v0.y, v1.y), v2.y), v3.y);
    m.z = fmaxf(fmaxf(fmaxf(v0.z, v1.z), v2.z), v3.z);
    m.w = fmaxf(fmaxf(fmaxf(v0.w, v1.w), v2.w), v3.w);

    f32x4* dst = (f32x4*)(out + (((long)n * NPOOL + py) * NPOOL + px) * FC + c4);
    __builtin_nontemporal_store(m, dst);
}

extern "C" void kernel_launch(void* const* d_in, const int* in_sizes, int n_in,
                              void* d_out, int out_size, void* d_ws, size_t ws_size,
                              hipStream_t stream) {
    const float* fmap     = (const float*)d_in[0];
    const float* rois     = (const float*)d_in[1];
    const int*   img_size = (const int*)d_in[2];
    float* out = (float*)d_out;

    const int N = in_sizes[1] / 4;   // rois is (N,4)
    const int blocks = N * NPOOL * NPOOL;
    roi_pool_kernel<<<blocks, 128, 0, stream>>>(fmap, rois, img_size, out, N);
}